// Round 1
// baseline (107.967 us; speedup 1.0000x reference)
//
#include <hip/hip_runtime.h>
#include <hip/hip_bf16.h>

typedef __bf16 bf16x8 __attribute__((ext_vector_type(8)));
typedef float  f32x4  __attribute__((ext_vector_type(4)));

#define NPROT 8192
#define NLIG  2048
#define DMODEL 128
#define NHEAD 8
#define DHEAD 16
#define NBATCH 32
#define PPB 256
#define LPB 64

__device__ __forceinline__ unsigned short f2bf(float f){
  union { float f; unsigned int u; } v; v.f = f;
  return (unsigned short)((v.u + 0x7FFFu + ((v.u >> 16) & 1u)) >> 16);
}

// ---------------- prep: f32 -> bf16 convert (+ optional transpose) ----------------
struct PrepJob {
  const float* src;
  unsigned short* dst;
  int elems, M, K, transpose, blockStart;
};
struct PrepArgs { int njobs; PrepJob jobs[20]; };

__global__ __launch_bounds__(256) void prep_kernel(PrepArgs args){
  int j = 0;
  while (j + 1 < args.njobs && (int)blockIdx.x >= args.jobs[j + 1].blockStart) ++j;
  const PrepJob jb = args.jobs[j];
  int idx = ((int)blockIdx.x - jb.blockStart) * 256 + (int)threadIdx.x;
  if (idx >= jb.elems) return;
  float v;
  if (jb.transpose){
    int m = idx / jb.K;
    int k = idx - m * jb.K;
    v = jb.src[(size_t)k * jb.M + m];   // src[K][M] -> dst[M][K]
  } else {
    v = jb.src[idx];
  }
  jb.dst[idx] = f2bf(v);
}

// ---------------- multi-job bf16 MFMA GEMM: C[N,M] = A[N,K] @ W_T[M,K]^T ----------------
struct GemmJob {
  const unsigned short* A;
  const unsigned short* W;
  const unsigned short* A2;   // optional second K-part (summed)
  const unsigned short* W2;
  const float* bias;          // [M] or null
  const float* resid;         // [N,M] or null
  float* outF;                // [N,M] or null
  unsigned short* outB;       // bf16 [N,M] or null
  int N, M, K, K2, relu, blockStart, tilesX;
};
struct GemmArgs { int njobs; GemmJob jobs[6]; };

__global__ __launch_bounds__(256) void gemm_kernel(GemmArgs args){
  int j = 0;
  while (j + 1 < args.njobs && (int)blockIdx.x >= args.jobs[j + 1].blockStart) ++j;
  const GemmJob jb = args.jobs[j];
  int t  = (int)blockIdx.x - jb.blockStart;
  int tn = t / jb.tilesX;
  int tm = t - tn * jb.tilesX;
  int w = (int)threadIdx.x >> 6;
  int l = (int)threadIdx.x & 63;
  int roff = tn * 64 + (w >> 1) * 32;
  int coff = tm * 64 + (w & 1) * 32;
  int lr = l & 15;
  int lk = (l >> 4) * 8;

  f32x4 acc00 = {0.f,0.f,0.f,0.f};
  f32x4 acc01 = acc00, acc10 = acc00, acc11 = acc00;

  for (int part = 0; part < 2; ++part){
    const unsigned short* Au = part ? jb.A2 : jb.A;
    const unsigned short* Wu = part ? jb.W2 : jb.W;
    if (!Au) break;
    int K = part ? jb.K2 : jb.K;
    const __bf16* Ab  = (const __bf16*)Au + (size_t)(roff + lr) * K + lk;
    const __bf16* Ab2 = Ab + (size_t)16 * K;
    const __bf16* Wb  = (const __bf16*)Wu + (size_t)(coff + lr) * K + lk;
    const __bf16* Wb2 = Wb + (size_t)16 * K;
    for (int kk = 0; kk < K; kk += 32){
      bf16x8 a0 = *(const bf16x8*)(Ab  + kk);
      bf16x8 a1 = *(const bf16x8*)(Ab2 + kk);
      bf16x8 b0 = *(const bf16x8*)(Wb  + kk);
      bf16x8 b1 = *(const bf16x8*)(Wb2 + kk);
      acc00 = __builtin_amdgcn_mfma_f32_16x16x32_bf16(a0, b0, acc00, 0, 0, 0);
      acc01 = __builtin_amdgcn_mfma_f32_16x16x32_bf16(a0, b1, acc01, 0, 0, 0);
      acc10 = __builtin_amdgcn_mfma_f32_16x16x32_bf16(a1, b0, acc10, 0, 0, 0);
      acc11 = __builtin_amdgcn_mfma_f32_16x16x32_bf16(a1, b1, acc11, 0, 0, 0);
    }
  }

  int M = jb.M;
  int rbase = roff + ((l >> 4) << 2);
  int c0 = coff + lr;
  int c1 = c0 + 16;
  float bias0 = jb.bias ? jb.bias[c0] : 0.f;
  float bias1 = jb.bias ? jb.bias[c1] : 0.f;
  f32x4 av[2][2] = {{acc00, acc01}, {acc10, acc11}};
  #pragma unroll
  for (int i = 0; i < 2; ++i){
    #pragma unroll
    for (int jj = 0; jj < 2; ++jj){
      int cc = jj ? c1 : c0;
      float bb = jj ? bias1 : bias0;
      #pragma unroll
      for (int e = 0; e < 4; ++e){
        int rr = rbase + i * 16 + e;
        float v = av[i][jj][e] + bb;
        if (jb.relu)  v = fmaxf(v, 0.f);
        if (jb.resid) v += jb.resid[(size_t)rr * M + cc];
        if (jb.outF)  jb.outF[(size_t)rr * M + cc] = v;
        if (jb.outB)  jb.outB[(size_t)rr * M + cc] = f2bf(v);
      }
    }
  }
}

// ---------------- attention: ligand queries (64) over protein keys (256) ----------------
__global__ __launch_bounds__(256) void attn_lig_kernel(
    const float* __restrict__ qkv_l, const float* __restrict__ qkv_p,
    float* __restrict__ ctx, unsigned short* __restrict__ ctxb)
{
  int b = (int)blockIdx.x >> 3;
  int h = (int)blockIdx.x & 7;
  __shared__ float Ks[PPB][16];
  __shared__ float Vs[PPB][16];
  __shared__ float pmax[4][64];
  __shared__ float psum[4][64];
  __shared__ float cpart[4][64][17];
  int tid = (int)threadIdx.x;
  {
    const float* src = qkv_p + ((size_t)(b * PPB + tid)) * 384 + 128 + h * 16;
    float4* kd = (float4*)&Ks[tid][0];
    float4* vd = (float4*)&Vs[tid][0];
    #pragma unroll
    for (int i = 0; i < 4; ++i) kd[i] = *(const float4*)(src + i * 4);
    #pragma unroll
    for (int i = 0; i < 4; ++i) vd[i] = *(const float4*)(src + 128 + i * 4);
  }
  __syncthreads();
  int s = tid >> 6;
  int r = tid & 63;
  float q[16];
  {
    const float* sq = qkv_l + ((size_t)(b * LPB + r)) * 384 + h * 16;
    #pragma unroll
    for (int i = 0; i < 4; ++i){
      float4 t4 = *(const float4*)(sq + i * 4);
      q[i*4+0] = t4.x; q[i*4+1] = t4.y; q[i*4+2] = t4.z; q[i*4+3] = t4.w;
    }
  }
  float sc[64];
  float pm = -1e30f;
  #pragma unroll
  for (int jj = 0; jj < 64; ++jj){
    int c = s * 64 + jj;
    const float4* kr = (const float4*)&Ks[c][0];
    float4 k0 = kr[0], k1 = kr[1], k2 = kr[2], k3 = kr[3];
    float dot = q[0]*k0.x + q[1]*k0.y + q[2]*k0.z + q[3]*k0.w
              + q[4]*k1.x + q[5]*k1.y + q[6]*k1.z + q[7]*k1.w
              + q[8]*k2.x + q[9]*k2.y + q[10]*k2.z + q[11]*k2.w
              + q[12]*k3.x + q[13]*k3.y + q[14]*k3.z + q[15]*k3.w;
    dot *= 0.25f;
    sc[jj] = dot;
    pm = fmaxf(pm, dot);
  }
  pmax[s][r] = pm;
  __syncthreads();
  float m = fmaxf(fmaxf(pmax[0][r], pmax[1][r]), fmaxf(pmax[2][r], pmax[3][r]));
  float ps = 0.f;
  float acc[16];
  #pragma unroll
  for (int d = 0; d < 16; ++d) acc[d] = 0.f;
  #pragma unroll
  for (int jj = 0; jj < 64; ++jj){
    int c = s * 64 + jj;
    float p = __expf(sc[jj] - m);
    ps += p;
    const float4* vr = (const float4*)&Vs[c][0];
    float4 v0 = vr[0], v1 = vr[1], v2 = vr[2], v3 = vr[3];
    acc[0]+=p*v0.x; acc[1]+=p*v0.y; acc[2]+=p*v0.z; acc[3]+=p*v0.w;
    acc[4]+=p*v1.x; acc[5]+=p*v1.y; acc[6]+=p*v1.z; acc[7]+=p*v1.w;
    acc[8]+=p*v2.x; acc[9]+=p*v2.y; acc[10]+=p*v2.z; acc[11]+=p*v2.w;
    acc[12]+=p*v3.x; acc[13]+=p*v3.y; acc[14]+=p*v3.z; acc[15]+=p*v3.w;
  }
  psum[s][r] = ps;
  #pragma unroll
  for (int d = 0; d < 16; ++d) cpart[s][r][d] = acc[d];
  __syncthreads();
  {
    int r2 = tid & 63;
    int dg = tid >> 6;
    float den = psum[0][r2] + psum[1][r2] + psum[2][r2] + psum[3][r2];
    float inv = 1.f / den;
    float o0 = (cpart[0][r2][dg*4+0]+cpart[1][r2][dg*4+0]+cpart[2][r2][dg*4+0]+cpart[3][r2][dg*4+0])*inv;
    float o1 = (cpart[0][r2][dg*4+1]+cpart[1][r2][dg*4+1]+cpart[2][r2][dg*4+1]+cpart[3][r2][dg*4+1])*inv;
    float o2 = (cpart[0][r2][dg*4+2]+cpart[1][r2][dg*4+2]+cpart[2][r2][dg*4+2]+cpart[3][r2][dg*4+2])*inv;
    float o3 = (cpart[0][r2][dg*4+3]+cpart[1][r2][dg*4+3]+cpart[2][r2][dg*4+3]+cpart[3][r2][dg*4+3])*inv;
    size_t base = ((size_t)(b * LPB + r2)) * DMODEL + h * 16 + dg * 4;
    *(float4*)(ctx + base) = make_float4(o0, o1, o2, o3);
    ushort4 u4; u4.x = f2bf(o0); u4.y = f2bf(o1); u4.z = f2bf(o2); u4.w = f2bf(o3);
    *(ushort4*)(ctxb + base) = u4;
  }
}

// ---------------- attention: protein queries (256) over ligand keys (64) ----------------
__global__ __launch_bounds__(256) void attn_prot_kernel(
    const float* __restrict__ qkv_p, const float* __restrict__ qkv_l,
    float* __restrict__ ctx, unsigned short* __restrict__ ctxb)
{
  int b = (int)blockIdx.x >> 3;
  int h = (int)blockIdx.x & 7;
  __shared__ float Ks[LPB][16];
  __shared__ float Vs[LPB][16];
  int tid = (int)threadIdx.x;
  if (tid < 128){
    int which = tid >> 6;
    int row = tid & 63;
    float (*arr)[16] = which ? Vs : Ks;
    const float* src = qkv_l + ((size_t)(b * LPB + row)) * 384 + 128 + which * 128 + h * 16;
    float4* dst = (float4*)&arr[row][0];
    #pragma unroll
    for (int i = 0; i < 4; ++i) dst[i] = *(const float4*)(src + i * 4);
  }
  __syncthreads();
  float q[16];
  {
    const float* sq = qkv_p + ((size_t)(b * PPB + tid)) * 384 + h * 16;
    #pragma unroll
    for (int i = 0; i < 4; ++i){
      float4 t4 = *(const float4*)(sq + i * 4);
      q[i*4+0] = t4.x; q[i*4+1] = t4.y; q[i*4+2] = t4.z; q[i*4+3] = t4.w;
    }
  }
  float sc[64];
  float pm = -1e30f;
  #pragma unroll
  for (int c = 0; c < 64; ++c){
    const float4* kr = (const float4*)&Ks[c][0];
    float4 k0 = kr[0], k1 = kr[1], k2 = kr[2], k3 = kr[3];
    float dot = q[0]*k0.x + q[1]*k0.y + q[2]*k0.z + q[3]*k0.w
              + q[4]*k1.x + q[5]*k1.y + q[6]*k1.z + q[7]*k1.w
              + q[8]*k2.x + q[9]*k2.y + q[10]*k2.z + q[11]*k2.w
              + q[12]*k3.x + q[13]*k3.y + q[14]*k3.z + q[15]*k3.w;
    dot *= 0.25f;
    sc[c] = dot;
    pm = fmaxf(pm, dot);
  }
  float ps = 0.f;
  float acc[16];
  #pragma unroll
  for (int d = 0; d < 16; ++d) acc[d] = 0.f;
  #pragma unroll
  for (int c = 0; c < 64; ++c){
    float p = __expf(sc[c] - pm);
    ps += p;
    const float4* vr = (const float4*)&Vs[c][0];
    float4 v0 = vr[0], v1 = vr[1], v2 = vr[2], v3 = vr[3];
    acc[0]+=p*v0.x; acc[1]+=p*v0.y; acc[2]+=p*v0.z; acc[3]+=p*v0.w;
    acc[4]+=p*v1.x; acc[5]+=p*v1.y; acc[6]+=p*v1.z; acc[7]+=p*v1.w;
    acc[8]+=p*v2.x; acc[9]+=p*v2.y; acc[10]+=p*v2.z; acc[11]+=p*v2.w;
    acc[12]+=p*v3.x; acc[13]+=p*v3.y; acc[14]+=p*v3.z; acc[15]+=p*v3.w;
  }
  float inv = 1.f / ps;
  size_t base = ((size_t)(b * PPB + tid)) * DMODEL + h * 16;
  #pragma unroll
  for (int i = 0; i < 4; ++i){
    float o0 = acc[i*4+0]*inv, o1 = acc[i*4+1]*inv, o2 = acc[i*4+2]*inv, o3 = acc[i*4+3]*inv;
    *(float4*)(ctx + base + i * 4) = make_float4(o0, o1, o2, o3);
    ushort4 u4; u4.x = f2bf(o0); u4.y = f2bf(o1); u4.z = f2bf(o2); u4.w = f2bf(o3);
    *(ushort4*)(ctxb + base + i * 4) = u4;
  }
}

// ---------------- gated update + LayerNorm (1 wave per row) ----------------
__global__ __launch_bounds__(256) void update_ln_kernel(
    const float* __restrict__ hP, const float* __restrict__ hL,
    const float* __restrict__ glP, const float* __restrict__ glL,
    const float* __restrict__ uP, const float* __restrict__ uL,
    const float* __restrict__ bgP, const float* __restrict__ bgL,
    const float* __restrict__ buP, const float* __restrict__ buL,
    const float* __restrict__ gP, const float* __restrict__ bP,
    const float* __restrict__ gL, const float* __restrict__ bL,
    float* __restrict__ huP, float* __restrict__ huL,
    unsigned short* __restrict__ xP, unsigned short* __restrict__ xL)
{
  int wave = (int)threadIdx.x >> 6;
  int l = (int)threadIdx.x & 63;
  int grow = (int)blockIdx.x * 4 + wave;
  const float *h, *gl, *u, *bg, *bu, *g, *bb;
  float* hu; unsigned short* x; int r;
  if (grow < NPROT){ r = grow;        h = hP; gl = glP; u = uP; bg = bgP; bu = buP; g = gP; bb = bP; hu = huP; x = xP; }
  else             { r = grow - NPROT; h = hL; gl = glL; u = uL; bg = bgL; bu = buL; g = gL; bb = bL; hu = huL; x = xL; }
  int c = l * 2;
  size_t base = (size_t)r * DMODEL + c;
  float2 hv = *(const float2*)(h + base);
  float2 gv = *(const float2*)(gl + base);
  float2 uv = *(const float2*)(u + base);
  float ga = 1.f / (1.f + __expf(-(gv.x + bg[c])));
  float gb = 1.f / (1.f + __expf(-(gv.y + bg[c+1])));
  float ua = uv.x + bu[c];
  float ub = uv.y + bu[c+1];
  float h0 = hv.x + ga * ua;
  float h1 = hv.y + gb * ub;
  *(float2*)(hu + base) = make_float2(h0, h1);
  float ssum = h0 + h1;
  #pragma unroll
  for (int o = 32; o > 0; o >>= 1) ssum += __shfl_xor(ssum, o);
  float mu = ssum * (1.f / 128.f);
  float d0 = h0 - mu, d1 = h1 - mu;
  float vs = d0 * d0 + d1 * d1;
  #pragma unroll
  for (int o = 32; o > 0; o >>= 1) vs += __shfl_xor(vs, o);
  float rs = rsqrtf(vs * (1.f / 128.f) + 1e-5f);
  float x0 = d0 * rs * g[c]   + bb[c];
  float x1 = d1 * rs * g[c+1] + bb[c+1];
  ushort2 o2; o2.x = f2bf(x0); o2.y = f2bf(x1);
  *(ushort2*)(x + base) = o2;
}

// ---------------- host ----------------
extern "C" void kernel_launch(void* const* d_in, const int* in_sizes, int n_in,
                              void* d_out, int out_size, void* d_ws, size_t ws_size,
                              hipStream_t stream) {
  (void)in_sizes; (void)n_in; (void)out_size; (void)ws_size;
  const float* h_p  = (const float*)d_in[0];
  const float* h_l  = (const float*)d_in[1];
  const float* Wq_l = (const float*)d_in[4];
  const float* Wk_p = (const float*)d_in[5];
  const float* Wv_p = (const float*)d_in[6];
  const float* Wg_l = (const float*)d_in[7];
  const float* bg_l = (const float*)d_in[8];
  const float* Wu_l = (const float*)d_in[9];
  const float* bu_l = (const float*)d_in[10];
  const float* Wq_p = (const float*)d_in[11];
  const float* Wk_l = (const float*)d_in[12];
  const float* Wv_l = (const float*)d_in[13];
  const float* Wg_p = (const float*)d_in[14];
  const float* bg_p = (const float*)d_in[15];
  const float* Wu_p = (const float*)d_in[16];
  const float* bu_p = (const float*)d_in[17];
  const float* ln_p_g = (const float*)d_in[18];
  const float* ln_p_b = (const float*)d_in[19];
  const float* ln_l_g = (const float*)d_in[20];
  const float* ln_l_b = (const float*)d_in[21];
  const float* W1_p = (const float*)d_in[22];
  const float* b1_p = (const float*)d_in[23];
  const float* W2_p = (const float*)d_in[24];
  const float* b2_p = (const float*)d_in[25];
  const float* W1_l = (const float*)d_in[26];
  const float* b1_l = (const float*)d_in[27];
  const float* W2_l = (const float*)d_in[28];
  const float* b2_l = (const float*)d_in[29];
  float* out = (float*)d_out;

  char* ws = (char*)d_ws;
  size_t off = 0;
  auto alloc = [&](size_t bytes) -> void* {
    void* p = ws + off; off += (bytes + 255) & ~(size_t)255; return p;
  };
  unsigned short* h_p_bf  = (unsigned short*)alloc((size_t)NPROT * DMODEL * 2);
  unsigned short* h_l_bf  = (unsigned short*)alloc((size_t)NLIG  * DMODEL * 2);
  unsigned short* projP_T = (unsigned short*)alloc((size_t)384 * 128 * 2);
  unsigned short* projL_T = (unsigned short*)alloc((size_t)384 * 128 * 2);
  unsigned short* WgT_p_T = (unsigned short*)alloc((size_t)128 * 128 * 2);
  unsigned short* WgB_p_T = (unsigned short*)alloc((size_t)128 * 128 * 2);
  unsigned short* Wu_p_T  = (unsigned short*)alloc((size_t)128 * 128 * 2);
  unsigned short* WgT_l_T = (unsigned short*)alloc((size_t)128 * 128 * 2);
  unsigned short* WgB_l_T = (unsigned short*)alloc((size_t)128 * 128 * 2);
  unsigned short* Wu_l_T  = (unsigned short*)alloc((size_t)128 * 128 * 2);
  unsigned short* W1_p_T  = (unsigned short*)alloc((size_t)512 * 128 * 2);
  unsigned short* W1_l_T  = (unsigned short*)alloc((size_t)512 * 128 * 2);
  unsigned short* W2_p_T  = (unsigned short*)alloc((size_t)128 * 512 * 2);
  unsigned short* W2_l_T  = (unsigned short*)alloc((size_t)128 * 512 * 2);
  float* qkv_p = (float*)alloc((size_t)NPROT * 384 * 4);
  float* qkv_l = (float*)alloc((size_t)NLIG  * 384 * 4);
  float* ctx_p = (float*)alloc((size_t)NPROT * DMODEL * 4);
  float* ctx_l = (float*)alloc((size_t)NLIG  * DMODEL * 4);
  unsigned short* ctx_p_bf = (unsigned short*)alloc((size_t)NPROT * DMODEL * 2);
  unsigned short* ctx_l_bf = (unsigned short*)alloc((size_t)NLIG  * DMODEL * 2);
  float* glin_p = (float*)alloc((size_t)NPROT * DMODEL * 4);
  float* glin_l = (float*)alloc((size_t)NLIG  * DMODEL * 4);
  float* u_p    = (float*)alloc((size_t)NPROT * DMODEL * 4);
  float* u_l    = (float*)alloc((size_t)NLIG  * DMODEL * 4);
  float* hu_p   = (float*)alloc((size_t)NPROT * DMODEL * 4);
  float* hu_l   = (float*)alloc((size_t)NLIG  * DMODEL * 4);
  unsigned short* xln_p = (unsigned short*)alloc((size_t)NPROT * DMODEL * 2);
  unsigned short* xln_l = (unsigned short*)alloc((size_t)NLIG  * DMODEL * 2);
  unsigned short* t_p   = (unsigned short*)alloc((size_t)NPROT * 512 * 2);
  unsigned short* t_l   = (unsigned short*)alloc((size_t)NLIG  * 512 * 2);

  // ---- prep ----
  PrepArgs pa; pa.njobs = 18;
  int pbs = 0;
  auto addPrep = [&](int i, const float* s, unsigned short* d, int elems, int M, int K, int tr){
    pa.jobs[i].src = s; pa.jobs[i].dst = d; pa.jobs[i].elems = elems;
    pa.jobs[i].M = M; pa.jobs[i].K = K; pa.jobs[i].transpose = tr; pa.jobs[i].blockStart = pbs;
    pbs += (elems + 255) / 256;
  };
  addPrep(0,  h_p, h_p_bf, NPROT * DMODEL, 0, 0, 0);
  addPrep(1,  h_l, h_l_bf, NLIG  * DMODEL, 0, 0, 0);
  addPrep(2,  Wq_l, projL_T + 0,        128 * 128, 128, 128, 1);
  addPrep(3,  Wk_l, projL_T + 128 * 128, 128 * 128, 128, 128, 1);
  addPrep(4,  Wv_l, projL_T + 256 * 128, 128 * 128, 128, 128, 1);
  addPrep(5,  Wq_p, projP_T + 0,        128 * 128, 128, 128, 1);
  addPrep(6,  Wk_p, projP_T + 128 * 128, 128 * 128, 128, 128, 1);
  addPrep(7,  Wv_p, projP_T + 256 * 128, 128 * 128, 128, 128, 1);
  addPrep(8,  Wg_l,             WgT_l_T, 128 * 128, 128, 128, 1);
  addPrep(9,  Wg_l + 128 * 128, WgB_l_T, 128 * 128, 128, 128, 1);
  addPrep(10, Wu_l,             Wu_l_T,  128 * 128, 128, 128, 1);
  addPrep(11, Wg_p,             WgT_p_T, 128 * 128, 128, 128, 1);
  addPrep(12, Wg_p + 128 * 128, WgB_p_T, 128 * 128, 128, 128, 1);
  addPrep(13, Wu_p,             Wu_p_T,  128 * 128, 128, 128, 1);
  addPrep(14, W1_p, W1_p_T, 128 * 512, 512, 128, 1);
  addPrep(15, W2_p, W2_p_T, 512 * 128, 128, 512, 1);
  addPrep(16, W1_l, W1_l_T, 128 * 512, 512, 128, 1);
  addPrep(17, W2_l, W2_l_T, 512 * 128, 128, 512, 1);
  prep_kernel<<<dim3(pbs), dim3(256), 0, stream>>>(pa);

  auto setGemm = [&](GemmJob& gj, const unsigned short* A, const unsigned short* W,
                     const unsigned short* A2, const unsigned short* W2,
                     int N, int M, int K, int K2,
                     const float* bias, const float* resid,
                     float* outF, unsigned short* outB, int relu, int& bstart){
    gj.A = A; gj.W = W; gj.A2 = A2; gj.W2 = W2;
    gj.bias = bias; gj.resid = resid; gj.outF = outF; gj.outB = outB;
    gj.N = N; gj.M = M; gj.K = K; gj.K2 = K2; gj.relu = relu;
    gj.blockStart = bstart; gj.tilesX = M / 64;
    bstart += (N / 64) * (M / 64);
  };

  // ---- QKV projections ----
  {
    GemmArgs ga; ga.njobs = 2; int b = 0;
    setGemm(ga.jobs[0], h_p_bf, projP_T, nullptr, nullptr, NPROT, 384, 128, 0,
            nullptr, nullptr, qkv_p, nullptr, 0, b);
    setGemm(ga.jobs[1], h_l_bf, projL_T, nullptr, nullptr, NLIG, 384, 128, 0,
            nullptr, nullptr, qkv_l, nullptr, 0, b);
    gemm_kernel<<<dim3(b), dim3(256), 0, stream>>>(ga);
  }

  // ---- attention ----
  attn_lig_kernel<<<dim3(NBATCH * NHEAD), dim3(256), 0, stream>>>(qkv_l, qkv_p, ctx_l, ctx_l_bf);
  attn_prot_kernel<<<dim3(NBATCH * NHEAD), dim3(256), 0, stream>>>(qkv_p, qkv_l, ctx_p, ctx_p_bf);

  // ---- gate linear (2-part K) + u linear ----
  {
    GemmArgs ga; ga.njobs = 4; int b = 0;
    setGemm(ga.jobs[0], h_p_bf, WgT_p_T, ctx_p_bf, WgB_p_T, NPROT, 128, 128, 128,
            nullptr, nullptr, glin_p, nullptr, 0, b);
    setGemm(ga.jobs[1], h_l_bf, WgT_l_T, ctx_l_bf, WgB_l_T, NLIG, 128, 128, 128,
            nullptr, nullptr, glin_l, nullptr, 0, b);
    setGemm(ga.jobs[2], ctx_p_bf, Wu_p_T, nullptr, nullptr, NPROT, 128, 128, 0,
            nullptr, nullptr, u_p, nullptr, 0, b);
    setGemm(ga.jobs[3], ctx_l_bf, Wu_l_T, nullptr, nullptr, NLIG, 128, 128, 0,
            nullptr, nullptr, u_l, nullptr, 0, b);
    gemm_kernel<<<dim3(b), dim3(256), 0, stream>>>(ga);
  }

  // ---- gated update + LayerNorm ----
  update_ln_kernel<<<dim3((NPROT + NLIG) / 4), dim3(256), 0, stream>>>(
      h_p, h_l, glin_p, glin_l, u_p, u_l, bg_p, bg_l, bu_p, bu_l,
      ln_p_g, ln_p_b, ln_l_g, ln_l_b, hu_p, hu_l, xln_p, xln_l);

  // ---- FFN layer 1 (relu, bf16 out) ----
  {
    GemmArgs ga; ga.njobs = 2; int b = 0;
    setGemm(ga.jobs[0], xln_p, W1_p_T, nullptr, nullptr, NPROT, 512, 128, 0,
            b1_p, nullptr, nullptr, t_p, 1, b);
    setGemm(ga.jobs[1], xln_l, W1_l_T, nullptr, nullptr, NLIG, 512, 128, 0,
            b1_l, nullptr, nullptr, t_l, 1, b);
    gemm_kernel<<<dim3(b), dim3(256), 0, stream>>>(ga);
  }

  // ---- FFN layer 2 (+bias +residual -> d_out) ----
  {
    GemmArgs ga; ga.njobs = 2; int b = 0;
    setGemm(ga.jobs[0], t_p, W2_p_T, nullptr, nullptr, NPROT, 128, 512, 0,
            b2_p, hu_p, out, nullptr, 0, b);
    setGemm(ga.jobs[1], t_l, W2_l_T, nullptr, nullptr, NLIG, 128, 512, 0,
            b2_l, hu_l, out + (size_t)NPROT * DMODEL, nullptr, 0, b);
    gemm_kernel<<<dim3(b), dim3(256), 0, stream>>>(ga);
  }
}

// Round 2
// 71.201 us; speedup vs baseline: 1.5164x; 1.5164x over previous
//
#include <hip/hip_runtime.h>
#include <hip/hip_bf16.h>

typedef __bf16 bf16x8 __attribute__((ext_vector_type(8)));
typedef float  f32x4  __attribute__((ext_vector_type(4)));

#define NPROT 8192
#define NLIG  2048
#define DMODEL 128
#define NHEAD 8
#define NBATCH 32
#define PPB 256
#define LPB 64
#define TR 32   // rows per tail block

__device__ __forceinline__ unsigned short f2bf(float f){
  union { float f; unsigned int u; } v; v.f = f;
  return (unsigned short)((v.u + 0x7FFFu + ((v.u >> 16) & 1u)) >> 16);
}

__device__ __forceinline__ void ldbf16x16(const unsigned short* p, float* o){
  bf16x8 v0 = *(const bf16x8*)p;
  bf16x8 v1 = *(const bf16x8*)(p + 8);
  #pragma unroll
  for (int i = 0; i < 8; ++i){ o[i] = (float)v0[i]; o[8 + i] = (float)v1[i]; }
}

// ---------------- prep: f32 -> bf16 convert (+ optional transpose) ----------------
struct PrepJob {
  const float* src; unsigned short* dst;
  int elems, M, K, transpose, blockStart;
};
struct PrepArgs { int njobs; PrepJob jobs[20]; };

__global__ __launch_bounds__(256) void prep_kernel(PrepArgs args){
  int j = 0;
  while (j + 1 < args.njobs && (int)blockIdx.x >= args.jobs[j + 1].blockStart) ++j;
  const PrepJob jb = args.jobs[j];
  int idx = ((int)blockIdx.x - jb.blockStart) * 256 + (int)threadIdx.x;
  if (idx >= jb.elems) return;
  float v;
  if (jb.transpose){
    int m = idx / jb.K;
    int k = idx - m * jb.K;
    v = jb.src[(size_t)k * jb.M + m];
  } else {
    v = jb.src[idx];
  }
  jb.dst[idx] = f2bf(v);
}

// ---------------- QKV GEMM: C[N,384] = A[N,128] @ W_T[384,128]^T, bf16 out ----------------
struct QkvJob { const unsigned short* A; const unsigned short* W; unsigned short* outB; int blockStart; };
struct QkvArgs { QkvJob jobs[2]; };

__global__ __launch_bounds__(256) void qkv_kernel(QkvArgs args){
  int j = ((int)blockIdx.x >= args.jobs[1].blockStart) ? 1 : 0;
  const QkvJob jb = args.jobs[j];
  int t  = (int)blockIdx.x - jb.blockStart;
  int tn = t / 6;
  int tm = t - tn * 6;
  int w = (int)threadIdx.x >> 6;
  int l = (int)threadIdx.x & 63;
  int roff = tn * 64 + (w >> 1) * 32;
  int coff = tm * 64 + (w & 1) * 32;
  int lr = l & 15;
  int lk = (l >> 4) * 8;
  f32x4 a00 = {0.f,0.f,0.f,0.f}, a01 = a00, a10 = a00, a11 = a00;
  const __bf16* Ab  = (const __bf16*)jb.A + (size_t)(roff + lr) * 128 + lk;
  const __bf16* Ab2 = Ab + 16 * 128;
  const __bf16* Wb  = (const __bf16*)jb.W + (size_t)(coff + lr) * 128 + lk;
  const __bf16* Wb2 = Wb + 16 * 128;
  #pragma unroll
  for (int kk = 0; kk < 128; kk += 32){
    bf16x8 a0 = *(const bf16x8*)(Ab  + kk);
    bf16x8 a1 = *(const bf16x8*)(Ab2 + kk);
    bf16x8 b0 = *(const bf16x8*)(Wb  + kk);
    bf16x8 b1 = *(const bf16x8*)(Wb2 + kk);
    a00 = __builtin_amdgcn_mfma_f32_16x16x32_bf16(a0, b0, a00, 0, 0, 0);
    a01 = __builtin_amdgcn_mfma_f32_16x16x32_bf16(a0, b1, a01, 0, 0, 0);
    a10 = __builtin_amdgcn_mfma_f32_16x16x32_bf16(a1, b0, a10, 0, 0, 0);
    a11 = __builtin_amdgcn_mfma_f32_16x16x32_bf16(a1, b1, a11, 0, 0, 0);
  }
  int rbase = roff + ((l >> 4) << 2);
  f32x4 av[2][2] = {{a00, a01}, {a10, a11}};
  #pragma unroll
  for (int i = 0; i < 2; ++i)
    #pragma unroll
    for (int jj = 0; jj < 2; ++jj)
      #pragma unroll
      for (int e = 0; e < 4; ++e){
        int rr = rbase + i * 16 + e;
        int cc = coff + jj * 16 + lr;
        jb.outB[(size_t)rr * 384 + cc] = f2bf(av[i][jj][e]);
      }
}

// ---------------- fused attention (both sides), bf16 in/out ----------------
__global__ __launch_bounds__(256) void attn_kernel(
    const unsigned short* __restrict__ qkv_p, const unsigned short* __restrict__ qkv_l,
    unsigned short* __restrict__ ctx_p, unsigned short* __restrict__ ctx_l)
{
  __shared__ float Ks[PPB][16];
  __shared__ float Vs[PPB][16];
  __shared__ float pmax[4][64];
  __shared__ float psum[4][64];
  __shared__ float cpart[4][64][17];
  int bid = (int)blockIdx.x;
  int tid = (int)threadIdx.x;
  if (bid < NBATCH * NHEAD){
    // ligand queries (64) over protein keys (256)
    int b = bid >> 3, h = bid & 7;
    {
      const unsigned short* src = qkv_p + ((size_t)(b * PPB + tid)) * 384 + 128 + h * 16;
      float tmp[16];
      ldbf16x16(src, tmp);
      #pragma unroll
      for (int i = 0; i < 16; ++i) Ks[tid][i] = tmp[i];
      ldbf16x16(src + 128, tmp);
      #pragma unroll
      for (int i = 0; i < 16; ++i) Vs[tid][i] = tmp[i];
    }
    __syncthreads();
    int s = tid >> 6;
    int r = tid & 63;
    float q[16];
    ldbf16x16(qkv_l + ((size_t)(b * LPB + r)) * 384 + h * 16, q);
    float sc[64];
    float pm = -1e30f;
    #pragma unroll
    for (int jj = 0; jj < 64; ++jj){
      int c = s * 64 + jj;
      float dot = 0.f;
      #pragma unroll
      for (int d = 0; d < 16; ++d) dot += q[d] * Ks[c][d];
      dot *= 0.25f;
      sc[jj] = dot;
      pm = fmaxf(pm, dot);
    }
    pmax[s][r] = pm;
    __syncthreads();
    float m = fmaxf(fmaxf(pmax[0][r], pmax[1][r]), fmaxf(pmax[2][r], pmax[3][r]));
    float ps = 0.f;
    float acc[16];
    #pragma unroll
    for (int d = 0; d < 16; ++d) acc[d] = 0.f;
    #pragma unroll
    for (int jj = 0; jj < 64; ++jj){
      int c = s * 64 + jj;
      float p = __expf(sc[jj] - m);
      ps += p;
      #pragma unroll
      for (int d = 0; d < 16; ++d) acc[d] += p * Vs[c][d];
    }
    psum[s][r] = ps;
    #pragma unroll
    for (int d = 0; d < 16; ++d) cpart[s][r][d] = acc[d];
    __syncthreads();
    {
      int r2 = tid & 63;
      int dg = tid >> 6;
      float den = psum[0][r2] + psum[1][r2] + psum[2][r2] + psum[3][r2];
      float inv = 1.f / den;
      ushort4 u4;
      float o0 = (cpart[0][r2][dg*4+0]+cpart[1][r2][dg*4+0]+cpart[2][r2][dg*4+0]+cpart[3][r2][dg*4+0])*inv;
      float o1 = (cpart[0][r2][dg*4+1]+cpart[1][r2][dg*4+1]+cpart[2][r2][dg*4+1]+cpart[3][r2][dg*4+1])*inv;
      float o2 = (cpart[0][r2][dg*4+2]+cpart[1][r2][dg*4+2]+cpart[2][r2][dg*4+2]+cpart[3][r2][dg*4+2])*inv;
      float o3 = (cpart[0][r2][dg*4+3]+cpart[1][r2][dg*4+3]+cpart[2][r2][dg*4+3]+cpart[3][r2][dg*4+3])*inv;
      u4.x = f2bf(o0); u4.y = f2bf(o1); u4.z = f2bf(o2); u4.w = f2bf(o3);
      *(ushort4*)(ctx_l + ((size_t)(b * LPB + r2)) * DMODEL + h * 16 + dg * 4) = u4;
    }
  } else {
    // protein queries (256) over ligand keys (64)
    int bb = bid - NBATCH * NHEAD;
    int b = bb >> 3, h = bb & 7;
    if (tid < 128){
      int which = tid >> 6;
      int row = tid & 63;
      const unsigned short* src = qkv_l + ((size_t)(b * LPB + row)) * 384 + 128 + which * 128 + h * 16;
      float tmp[16];
      ldbf16x16(src, tmp);
      if (which){
        #pragma unroll
        for (int i = 0; i < 16; ++i) Vs[row][i] = tmp[i];
      } else {
        #pragma unroll
        for (int i = 0; i < 16; ++i) Ks[row][i] = tmp[i];
      }
    }
    __syncthreads();
    float q[16];
    ldbf16x16(qkv_p + ((size_t)(b * PPB + tid)) * 384 + h * 16, q);
    float sc[64];
    float pm = -1e30f;
    #pragma unroll
    for (int c = 0; c < 64; ++c){
      float dot = 0.f;
      #pragma unroll
      for (int d = 0; d < 16; ++d) dot += q[d] * Ks[c][d];
      dot *= 0.25f;
      sc[c] = dot;
      pm = fmaxf(pm, dot);
    }
    float ps = 0.f;
    float acc[16];
    #pragma unroll
    for (int d = 0; d < 16; ++d) acc[d] = 0.f;
    #pragma unroll
    for (int c = 0; c < 64; ++c){
      float p = __expf(sc[c] - pm);
      ps += p;
      #pragma unroll
      for (int d = 0; d < 16; ++d) acc[d] += p * Vs[c][d];
    }
    float inv = 1.f / ps;
    size_t base = ((size_t)(b * PPB + tid)) * DMODEL + h * 16;
    #pragma unroll
    for (int i = 0; i < 4; ++i){
      ushort4 u4;
      u4.x = f2bf(acc[i*4+0]*inv); u4.y = f2bf(acc[i*4+1]*inv);
      u4.z = f2bf(acc[i*4+2]*inv); u4.w = f2bf(acc[i*4+3]*inv);
      *(ushort4*)(ctx_p + base + i * 4) = u4;
    }
  }
}

// ---------------- fused tail: gate+u GEMM -> gating -> LN -> FFN1 -> FFN2 ----------------
struct TailArgs {
  const unsigned short *h_bf[2], *ctx_bf[2];
  const float *h_f[2];
  const unsigned short *WgT[2], *WgB[2], *WuT[2];
  const float *bg[2], *bu[2], *lng[2], *lnb[2];
  const unsigned short *W1T[2], *W2T[2];
  const float *b1[2], *b2[2];
  float* out[2];
};

__global__ __launch_bounds__(256) void tail_kernel(TailArgs args){
  __shared__ float hu_s[TR][132];
  __shared__ unsigned short xln_s[TR][136];
  __shared__ unsigned short t_s[TR][520];

  int bid = (int)blockIdx.x;
  int side = (bid < NPROT / TR) ? 0 : 1;
  int rowbase = (side ? bid - NPROT / TR : bid) * TR;
  int w = (int)threadIdx.x >> 6;
  int l = (int)threadIdx.x & 63;
  int lr = l & 15;
  int lk = (l >> 4) * 8;

  // ---- stage 1: glin (K=256: h|ctx) and u (K=128: ctx) for 32x128 stripe ----
  {
    f32x4 g[2][2], u[2][2];
    #pragma unroll
    for (int i = 0; i < 2; ++i)
      #pragma unroll
      for (int jj = 0; jj < 2; ++jj){ g[i][jj] = (f32x4){0.f,0.f,0.f,0.f}; u[i][jj] = g[i][jj]; }
    const __bf16* Ah = (const __bf16*)args.h_bf[side]   + (size_t)(rowbase + lr) * 128 + lk;
    const __bf16* Ac = (const __bf16*)args.ctx_bf[side] + (size_t)(rowbase + lr) * 128 + lk;
    const __bf16* Bg = (const __bf16*)args.WgT[side] + (size_t)(w * 32 + lr) * 128 + lk;
    const __bf16* Bc = (const __bf16*)args.WgB[side] + (size_t)(w * 32 + lr) * 128 + lk;
    const __bf16* Bu = (const __bf16*)args.WuT[side] + (size_t)(w * 32 + lr) * 128 + lk;
    #pragma unroll
    for (int kk = 0; kk < 128; kk += 32){
      bf16x8 ah0 = *(const bf16x8*)(Ah + kk);
      bf16x8 ah1 = *(const bf16x8*)(Ah + 16 * 128 + kk);
      bf16x8 ac0 = *(const bf16x8*)(Ac + kk);
      bf16x8 ac1 = *(const bf16x8*)(Ac + 16 * 128 + kk);
      bf16x8 bg0 = *(const bf16x8*)(Bg + kk);
      bf16x8 bg1 = *(const bf16x8*)(Bg + 16 * 128 + kk);
      bf16x8 bc0 = *(const bf16x8*)(Bc + kk);
      bf16x8 bc1 = *(const bf16x8*)(Bc + 16 * 128 + kk);
      bf16x8 bu0 = *(const bf16x8*)(Bu + kk);
      bf16x8 bu1 = *(const bf16x8*)(Bu + 16 * 128 + kk);
      g[0][0] = __builtin_amdgcn_mfma_f32_16x16x32_bf16(ah0, bg0, g[0][0], 0, 0, 0);
      g[0][1] = __builtin_amdgcn_mfma_f32_16x16x32_bf16(ah0, bg1, g[0][1], 0, 0, 0);
      g[1][0] = __builtin_amdgcn_mfma_f32_16x16x32_bf16(ah1, bg0, g[1][0], 0, 0, 0);
      g[1][1] = __builtin_amdgcn_mfma_f32_16x16x32_bf16(ah1, bg1, g[1][1], 0, 0, 0);
      g[0][0] = __builtin_amdgcn_mfma_f32_16x16x32_bf16(ac0, bc0, g[0][0], 0, 0, 0);
      g[0][1] = __builtin_amdgcn_mfma_f32_16x16x32_bf16(ac0, bc1, g[0][1], 0, 0, 0);
      g[1][0] = __builtin_amdgcn_mfma_f32_16x16x32_bf16(ac1, bc0, g[1][0], 0, 0, 0);
      g[1][1] = __builtin_amdgcn_mfma_f32_16x16x32_bf16(ac1, bc1, g[1][1], 0, 0, 0);
      u[0][0] = __builtin_amdgcn_mfma_f32_16x16x32_bf16(ac0, bu0, u[0][0], 0, 0, 0);
      u[0][1] = __builtin_amdgcn_mfma_f32_16x16x32_bf16(ac0, bu1, u[0][1], 0, 0, 0);
      u[1][0] = __builtin_amdgcn_mfma_f32_16x16x32_bf16(ac1, bu0, u[1][0], 0, 0, 0);
      u[1][1] = __builtin_amdgcn_mfma_f32_16x16x32_bf16(ac1, bu1, u[1][1], 0, 0, 0);
    }
    const float* hf = args.h_f[side];
    const float* bgv = args.bg[side];
    const float* buv = args.bu[side];
    #pragma unroll
    for (int i = 0; i < 2; ++i)
      #pragma unroll
      for (int jj = 0; jj < 2; ++jj)
        #pragma unroll
        for (int e = 0; e < 4; ++e){
          int row = i * 16 + ((l >> 4) << 2) + e;
          int col = w * 32 + jj * 16 + lr;
          float gv = g[i][jj][e] + bgv[col];
          float uv = u[i][jj][e] + buv[col];
          float hv = hf[(size_t)(rowbase + row) * 128 + col];
          float sg = 1.f / (1.f + __expf(-gv));
          hu_s[row][col] = hv + sg * uv;
        }
  }
  __syncthreads();

  // ---- stage 2: per-row LayerNorm -> xln (bf16, XOR-swizzled) ----
  {
    int r = (int)threadIdx.x >> 3;
    int sub = (int)threadIdx.x & 7;
    float x[16];
    #pragma unroll
    for (int i = 0; i < 4; ++i){
      float4 v4 = *(const float4*)&hu_s[r][sub * 16 + i * 4];
      x[i*4+0] = v4.x; x[i*4+1] = v4.y; x[i*4+2] = v4.z; x[i*4+3] = v4.w;
    }
    float s = 0.f;
    #pragma unroll
    for (int i = 0; i < 16; ++i) s += x[i];
    s += __shfl_xor(s, 1); s += __shfl_xor(s, 2); s += __shfl_xor(s, 4);
    float mu = s * (1.f / 128.f);
    float vv = 0.f;
    #pragma unroll
    for (int i = 0; i < 16; ++i){ float d = x[i] - mu; vv += d * d; }
    vv += __shfl_xor(vv, 1); vv += __shfl_xor(vv, 2); vv += __shfl_xor(vv, 4);
    float rs = rsqrtf(vv * (1.f / 128.f) + 1e-5f);
    const float* lg = args.lng[side];
    const float* lb = args.lnb[side];
    int sw = (r & 7) << 3;
    #pragma unroll
    for (int i = 0; i < 16; ++i){
      int col = sub * 16 + i;
      xln_s[r][col ^ sw] = f2bf((x[i] - mu) * rs * lg[col] + lb[col]);
    }
  }
  __syncthreads();

  // ---- stage 3: FFN1 t[32,512] = relu(xln @ W1 + b1), bf16 swizzled LDS ----
  {
    f32x4 acc[2][8];
    #pragma unroll
    for (int i = 0; i < 2; ++i)
      #pragma unroll
      for (int jj = 0; jj < 8; ++jj) acc[i][jj] = (f32x4){0.f,0.f,0.f,0.f};
    const __bf16* B1 = (const __bf16*)args.W1T[side] + (size_t)(w * 128 + lr) * 128 + lk;
    int sw0 = (lr & 7) << 3;
    #pragma unroll
    for (int kk = 0; kk < 128; kk += 32){
      bf16x8 a0 = *(const bf16x8*)&xln_s[lr][(kk + lk) ^ sw0];
      bf16x8 a1 = *(const bf16x8*)&xln_s[16 + lr][(kk + lk) ^ sw0];
      #pragma unroll
      for (int jj = 0; jj < 8; ++jj){
        bf16x8 b = *(const bf16x8*)(B1 + (size_t)jj * 16 * 128 + kk);
        acc[0][jj] = __builtin_amdgcn_mfma_f32_16x16x32_bf16(a0, b, acc[0][jj], 0, 0, 0);
        acc[1][jj] = __builtin_amdgcn_mfma_f32_16x16x32_bf16(a1, b, acc[1][jj], 0, 0, 0);
      }
    }
    const float* b1v = args.b1[side];
    #pragma unroll
    for (int i = 0; i < 2; ++i)
      #pragma unroll
      for (int jj = 0; jj < 8; ++jj)
        #pragma unroll
        for (int e = 0; e < 4; ++e){
          int row = i * 16 + ((l >> 4) << 2) + e;
          int col = w * 128 + jj * 16 + lr;
          float v = fmaxf(acc[i][jj][e] + b1v[col], 0.f);
          t_s[row][col ^ ((row & 7) << 3)] = f2bf(v);
        }
  }
  __syncthreads();

  // ---- stage 4: FFN2 out[32,128] = t @ W2 + b2 + hu ----
  {
    f32x4 o[2][2];
    #pragma unroll
    for (int i = 0; i < 2; ++i)
      #pragma unroll
      for (int jj = 0; jj < 2; ++jj) o[i][jj] = (f32x4){0.f,0.f,0.f,0.f};
    const __bf16* B2 = (const __bf16*)args.W2T[side] + (size_t)(w * 32 + lr) * 512 + lk;
    int sw0 = (lr & 7) << 3;
    #pragma unroll
    for (int kk = 0; kk < 512; kk += 32){
      bf16x8 a0 = *(const bf16x8*)&t_s[lr][(kk + lk) ^ sw0];
      bf16x8 a1 = *(const bf16x8*)&t_s[16 + lr][(kk + lk) ^ sw0];
      bf16x8 b0 = *(const bf16x8*)(B2 + kk);
      bf16x8 b1 = *(const bf16x8*)(B2 + (size_t)16 * 512 + kk);
      o[0][0] = __builtin_amdgcn_mfma_f32_16x16x32_bf16(a0, b0, o[0][0], 0, 0, 0);
      o[0][1] = __builtin_amdgcn_mfma_f32_16x16x32_bf16(a0, b1, o[0][1], 0, 0, 0);
      o[1][0] = __builtin_amdgcn_mfma_f32_16x16x32_bf16(a1, b0, o[1][0], 0, 0, 0);
      o[1][1] = __builtin_amdgcn_mfma_f32_16x16x32_bf16(a1, b1, o[1][1], 0, 0, 0);
    }
    const float* b2v = args.b2[side];
    float* outp = args.out[side];
    #pragma unroll
    for (int i = 0; i < 2; ++i)
      #pragma unroll
      for (int jj = 0; jj < 2; ++jj)
        #pragma unroll
        for (int e = 0; e < 4; ++e){
          int row = i * 16 + ((l >> 4) << 2) + e;
          int col = w * 32 + jj * 16 + lr;
          outp[(size_t)(rowbase + row) * 128 + col] = o[i][jj][e] + b2v[col] + hu_s[row][col];
        }
  }
}

// ---------------- host ----------------
extern "C" void kernel_launch(void* const* d_in, const int* in_sizes, int n_in,
                              void* d_out, int out_size, void* d_ws, size_t ws_size,
                              hipStream_t stream) {
  (void)in_sizes; (void)n_in; (void)out_size; (void)ws_size;
  const float* h_p  = (const float*)d_in[0];
  const float* h_l  = (const float*)d_in[1];
  const float* Wq_l = (const float*)d_in[4];
  const float* Wk_p = (const float*)d_in[5];
  const float* Wv_p = (const float*)d_in[6];
  const float* Wg_l = (const float*)d_in[7];
  const float* bg_l = (const float*)d_in[8];
  const float* Wu_l = (const float*)d_in[9];
  const float* bu_l = (const float*)d_in[10];
  const float* Wq_p = (const float*)d_in[11];
  const float* Wk_l = (const float*)d_in[12];
  const float* Wv_l = (const float*)d_in[13];
  const float* Wg_p = (const float*)d_in[14];
  const float* bg_p = (const float*)d_in[15];
  const float* Wu_p = (const float*)d_in[16];
  const float* bu_p = (const float*)d_in[17];
  const float* ln_p_g = (const float*)d_in[18];
  const float* ln_p_b = (const float*)d_in[19];
  const float* ln_l_g = (const float*)d_in[20];
  const float* ln_l_b = (const float*)d_in[21];
  const float* W1_p = (const float*)d_in[22];
  const float* b1_p = (const float*)d_in[23];
  const float* W2_p = (const float*)d_in[24];
  const float* b2_p = (const float*)d_in[25];
  const float* W1_l = (const float*)d_in[26];
  const float* b1_l = (const float*)d_in[27];
  const float* W2_l = (const float*)d_in[28];
  const float* b2_l = (const float*)d_in[29];
  float* out = (float*)d_out;

  char* ws = (char*)d_ws;
  size_t off = 0;
  auto alloc = [&](size_t bytes) -> void* {
    void* p = ws + off; off += (bytes + 255) & ~(size_t)255; return p;
  };
  unsigned short* h_p_bf  = (unsigned short*)alloc((size_t)NPROT * DMODEL * 2);
  unsigned short* h_l_bf  = (unsigned short*)alloc((size_t)NLIG  * DMODEL * 2);
  unsigned short* projP_T = (unsigned short*)alloc((size_t)384 * 128 * 2);
  unsigned short* projL_T = (unsigned short*)alloc((size_t)384 * 128 * 2);
  unsigned short* WgT_p_T = (unsigned short*)alloc((size_t)128 * 128 * 2);
  unsigned short* WgB_p_T = (unsigned short*)alloc((size_t)128 * 128 * 2);
  unsigned short* Wu_p_T  = (unsigned short*)alloc((size_t)128 * 128 * 2);
  unsigned short* WgT_l_T = (unsigned short*)alloc((size_t)128 * 128 * 2);
  unsigned short* WgB_l_T = (unsigned short*)alloc((size_t)128 * 128 * 2);
  unsigned short* Wu_l_T  = (unsigned short*)alloc((size_t)128 * 128 * 2);
  unsigned short* W1_p_T  = (unsigned short*)alloc((size_t)512 * 128 * 2);
  unsigned short* W1_l_T  = (unsigned short*)alloc((size_t)512 * 128 * 2);
  unsigned short* W2_p_T  = (unsigned short*)alloc((size_t)128 * 512 * 2);
  unsigned short* W2_l_T  = (unsigned short*)alloc((size_t)128 * 512 * 2);
  unsigned short* qkv_p   = (unsigned short*)alloc((size_t)NPROT * 384 * 2);
  unsigned short* qkv_l   = (unsigned short*)alloc((size_t)NLIG  * 384 * 2);
  unsigned short* ctx_p_bf = (unsigned short*)alloc((size_t)NPROT * DMODEL * 2);
  unsigned short* ctx_l_bf = (unsigned short*)alloc((size_t)NLIG  * DMODEL * 2);

  // ---- prep ----
  PrepArgs pa; pa.njobs = 18;
  int pbs = 0;
  auto addPrep = [&](int i, const float* s, unsigned short* d, int elems, int M, int K, int tr){
    pa.jobs[i].src = s; pa.jobs[i].dst = d; pa.jobs[i].elems = elems;
    pa.jobs[i].M = M; pa.jobs[i].K = K; pa.jobs[i].transpose = tr; pa.jobs[i].blockStart = pbs;
    pbs += (elems + 255) / 256;
  };
  addPrep(0,  h_p, h_p_bf, NPROT * DMODEL, 0, 0, 0);
  addPrep(1,  h_l, h_l_bf, NLIG  * DMODEL, 0, 0, 0);
  addPrep(2,  Wq_l, projL_T + 0,         128 * 128, 128, 128, 1);
  addPrep(3,  Wk_l, projL_T + 128 * 128, 128 * 128, 128, 128, 1);
  addPrep(4,  Wv_l, projL_T + 256 * 128, 128 * 128, 128, 128, 1);
  addPrep(5,  Wq_p, projP_T + 0,         128 * 128, 128, 128, 1);
  addPrep(6,  Wk_p, projP_T + 128 * 128, 128 * 128, 128, 128, 1);
  addPrep(7,  Wv_p, projP_T + 256 * 128, 128 * 128, 128, 128, 1);
  addPrep(8,  Wg_l,             WgT_l_T, 128 * 128, 128, 128, 1);
  addPrep(9,  Wg_l + 128 * 128, WgB_l_T, 128 * 128, 128, 128, 1);
  addPrep(10, Wu_l,             Wu_l_T,  128 * 128, 128, 128, 1);
  addPrep(11, Wg_p,             WgT_p_T, 128 * 128, 128, 128, 1);
  addPrep(12, Wg_p + 128 * 128, WgB_p_T, 128 * 128, 128, 128, 1);
  addPrep(13, Wu_p,             Wu_p_T,  128 * 128, 128, 128, 1);
  addPrep(14, W1_p, W1_p_T, 128 * 512, 512, 128, 1);
  addPrep(15, W2_p, W2_p_T, 512 * 128, 128, 512, 1);
  addPrep(16, W1_l, W1_l_T, 128 * 512, 512, 128, 1);
  addPrep(17, W2_l, W2_l_T, 512 * 128, 128, 512, 1);
  prep_kernel<<<dim3(pbs), dim3(256), 0, stream>>>(pa);

  // ---- QKV projections (bf16 out) ----
  {
    QkvArgs qa;
    qa.jobs[0] = { h_p_bf, projP_T, qkv_p, 0 };
    qa.jobs[1] = { h_l_bf, projL_T, qkv_l, (NPROT / 64) * 6 };
    int nb = (NPROT / 64) * 6 + (NLIG / 64) * 6;
    qkv_kernel<<<dim3(nb), dim3(256), 0, stream>>>(qa);
  }

  // ---- fused attention, both sides ----
  attn_kernel<<<dim3(2 * NBATCH * NHEAD), dim3(256), 0, stream>>>(qkv_p, qkv_l, ctx_p_bf, ctx_l_bf);

  // ---- fused tail ----
  {
    TailArgs ta;
    ta.h_bf[0] = h_p_bf;  ta.h_bf[1] = h_l_bf;
    ta.ctx_bf[0] = ctx_p_bf; ta.ctx_bf[1] = ctx_l_bf;
    ta.h_f[0] = h_p; ta.h_f[1] = h_l;
    ta.WgT[0] = WgT_p_T; ta.WgT[1] = WgT_l_T;
    ta.WgB[0] = WgB_p_T; ta.WgB[1] = WgB_l_T;
    ta.WuT[0] = Wu_p_T;  ta.WuT[1] = Wu_l_T;
    ta.bg[0] = bg_p; ta.bg[1] = bg_l;
    ta.bu[0] = bu_p; ta.bu[1] = bu_l;
    ta.lng[0] = ln_p_g; ta.lng[1] = ln_l_g;
    ta.lnb[0] = ln_p_b; ta.lnb[1] = ln_l_b;
    ta.W1T[0] = W1_p_T; ta.W1T[1] = W1_l_T;
    ta.W2T[0] = W2_p_T; ta.W2T[1] = W2_l_T;
    ta.b1[0] = b1_p; ta.b1[1] = b1_l;
    ta.b2[0] = b2_p; ta.b2[1] = b2_l;
    ta.out[0] = out; ta.out[1] = out + (size_t)NPROT * DMODEL;
    tail_kernel<<<dim3(NPROT / TR + NLIG / TR), dim3(256), 0, stream>>>(ta);
  }
}

// Round 3
// 67.736 us; speedup vs baseline: 1.5939x; 1.0512x over previous
//
#include <hip/hip_runtime.h>
#include <hip/hip_bf16.h>

typedef __bf16 bf16x8 __attribute__((ext_vector_type(8)));
typedef __bf16 bf16x4 __attribute__((ext_vector_type(4)));
typedef float  f32x4  __attribute__((ext_vector_type(4)));
typedef unsigned short u16;

#define NPROT 8192
#define NLIG  2048
#define DMODEL 128
#define NHEAD 8
#define NBATCH 32
#define PPB 256
#define LPB 64
#define TR 32

__device__ __forceinline__ u16 f2bf(float f){
  union { float f; unsigned int u; } v; v.f = f;
  return (u16)((v.u + 0x7FFFu + ((v.u >> 16) & 1u)) >> 16);
}

__device__ __forceinline__ bf16x8 cvt8(const float* p){
  float4 a = *(const float4*)p, b = *(const float4*)(p + 4);
  bf16x8 r;
  r[0]=(__bf16)a.x; r[1]=(__bf16)a.y; r[2]=(__bf16)a.z; r[3]=(__bf16)a.w;
  r[4]=(__bf16)b.x; r[5]=(__bf16)b.y; r[6]=(__bf16)b.z; r[7]=(__bf16)b.w;
  return r;
}

// ---------------- prep: coalesced LDS-tiled transpose f32[K][M] -> bf16[M][K] ----------------
struct TJob { const float* src; u16* dst; int M, K, tilesX, blockStart; };
struct TArgs { int njobs; TJob jobs[16]; };

__global__ __launch_bounds__(256) void prep_kernel(TArgs args){
  int j = 0;
  while (j + 1 < args.njobs && (int)blockIdx.x >= args.jobs[j + 1].blockStart) ++j;
  const TJob jb = args.jobs[j];
  int t = (int)blockIdx.x - jb.blockStart;
  int tm = t % jb.tilesX, tk = t / jb.tilesX;
  __shared__ float tile[32][33];
  int c = (int)threadIdx.x & 31, r0 = (int)threadIdx.x >> 5;
  #pragma unroll
  for (int p = 0; p < 4; ++p)
    tile[r0 + p * 8][c] = jb.src[(size_t)(tk * 32 + r0 + p * 8) * jb.M + tm * 32 + c];
  __syncthreads();
  #pragma unroll
  for (int p = 0; p < 4; ++p)
    jb.dst[(size_t)(tm * 32 + r0 + p * 8) * jb.K + tk * 32 + c] = f2bf(tile[c][r0 + p * 8]);
}

// ---------------- QKV GEMM: C[N,384] = A_f32[N,128] @ W_T[384,128]^T, bf16 out ----------------
struct QkvJob { const float* A; const u16* W; u16* outB; int blockStart; };
struct QkvArgs { QkvJob jobs[2]; };

__global__ __launch_bounds__(256) void qkv_kernel(QkvArgs args){
  int j = ((int)blockIdx.x >= args.jobs[1].blockStart) ? 1 : 0;
  const QkvJob jb = args.jobs[j];
  int t  = (int)blockIdx.x - jb.blockStart;
  int tn = t / 6;
  int tm = t - tn * 6;
  int w = (int)threadIdx.x >> 6;
  int l = (int)threadIdx.x & 63;
  int roff = tn * 64 + (w >> 1) * 32;
  int coff = tm * 64 + (w & 1) * 32;
  int lr = l & 15;
  int lk = (l >> 4) * 8;
  f32x4 a00 = {0.f,0.f,0.f,0.f}, a01 = a00, a10 = a00, a11 = a00;
  const float* Af  = jb.A + (size_t)(roff + lr) * 128 + lk;
  const float* Af2 = Af + 16 * 128;
  const __bf16* Wb  = (const __bf16*)jb.W + (size_t)(coff + lr) * 128 + lk;
  const __bf16* Wb2 = Wb + 16 * 128;
  #pragma unroll
  for (int kk = 0; kk < 128; kk += 32){
    bf16x8 a0 = cvt8(Af + kk);
    bf16x8 a1 = cvt8(Af2 + kk);
    bf16x8 b0 = *(const bf16x8*)(Wb  + kk);
    bf16x8 b1 = *(const bf16x8*)(Wb2 + kk);
    a00 = __builtin_amdgcn_mfma_f32_16x16x32_bf16(a0, b0, a00, 0, 0, 0);
    a01 = __builtin_amdgcn_mfma_f32_16x16x32_bf16(a0, b1, a01, 0, 0, 0);
    a10 = __builtin_amdgcn_mfma_f32_16x16x32_bf16(a1, b0, a10, 0, 0, 0);
    a11 = __builtin_amdgcn_mfma_f32_16x16x32_bf16(a1, b1, a11, 0, 0, 0);
  }
  int rbase = roff + ((l >> 4) << 2);
  f32x4 av[2][2] = {{a00, a01}, {a10, a11}};
  #pragma unroll
  for (int i = 0; i < 2; ++i)
    #pragma unroll
    for (int jj = 0; jj < 2; ++jj)
      #pragma unroll
      for (int e = 0; e < 4; ++e){
        int rr = rbase + i * 16 + e;
        int cc = coff + jj * 16 + lr;
        jb.outB[(size_t)rr * 384 + cc] = f2bf(av[i][jj][e]);
      }
}

// ---------------- fused MFMA attention per (batch, head), both directions ----------------
__global__ __launch_bounds__(256) void attn_kernel(
    const u16* __restrict__ qkv_p, const u16* __restrict__ qkv_l,
    u16* __restrict__ ctx_p, u16* __restrict__ ctx_l)
{
  int b = (int)blockIdx.x >> 3, h = (int)blockIdx.x & 7;
  int tid = (int)threadIdx.x, w = tid >> 6, l = tid & 63;
  int lr = l & 15, lg = l >> 4;

  __shared__ u16 P_s[256 * 72];    // prot: [256][72]; lig view: [64][264]
  __shared__ u16 vT_s[16 * 264];   // lig: [16][264]; prot view: [16][72]
  __shared__ float cpart[4][64][17];
  __shared__ float redA[4][4][16];
  __shared__ float redB[4][4][16];
  __shared__ float den[256];

  const u16* qp = qkv_p + (size_t)b * PPB * 384;
  const u16* ql = qkv_l + (size_t)b * LPB * 384;

  bf16x8 zero8;
  #pragma unroll
  for (int i = 0; i < 8; ++i) zero8[i] = (__bf16)0.f;

  // ---- build protein V^T in LDS: vT[d][key] ----
  {
    const u16* src = qp + (size_t)tid * 384 + 256 + h * 16;
    bf16x8 v0 = *(const bf16x8*)src;
    bf16x8 v1 = *(const bf16x8*)(src + 8);
    #pragma unroll
    for (int i = 0; i < 8; ++i){
      vT_s[i * 264 + tid]       = ((const u16*)&v0)[i];
      vT_s[(i + 8) * 264 + tid] = ((const u16*)&v1)[i];
    }
  }

  // ---- ligand-side S^T = k_p @ q_l^T  (keys split across waves) ----
  f32x4 acc[4][4];
  #pragma unroll
  for (int kt = 0; kt < 4; ++kt)
    #pragma unroll
    for (int qt = 0; qt < 4; ++qt) acc[kt][qt] = (f32x4){0.f,0.f,0.f,0.f};
  {
    bf16x8 afr[4], bfr[4];
    #pragma unroll
    for (int kt = 0; kt < 4; ++kt)
      afr[kt] = (l < 32) ? *(const bf16x8*)(qp + (size_t)(w * 64 + kt * 16 + lr) * 384 + 128 + h * 16 + lg * 8) : zero8;
    #pragma unroll
    for (int qt = 0; qt < 4; ++qt)
      bfr[qt] = (l < 32) ? *(const bf16x8*)(ql + (size_t)(qt * 16 + lr) * 384 + h * 16 + lg * 8) : zero8;
    #pragma unroll
    for (int kt = 0; kt < 4; ++kt)
      #pragma unroll
      for (int qt = 0; qt < 4; ++qt)
        acc[kt][qt] = __builtin_amdgcn_mfma_f32_16x16x32_bf16(afr[kt], bfr[qt], acc[kt][qt], 0, 0, 0);
  }
  // per-query max over this wave's 64 keys
  float qmax[4];
  #pragma unroll
  for (int qt = 0; qt < 4; ++qt){
    float m = -1e30f;
    #pragma unroll
    for (int kt = 0; kt < 4; ++kt)
      #pragma unroll
      for (int e = 0; e < 4; ++e) m = fmaxf(m, acc[kt][qt][e]);
    m = fmaxf(m, __shfl_xor(m, 16)); m = fmaxf(m, __shfl_xor(m, 32));
    qmax[qt] = m;
    if (l < 16) redA[w][qt][lr] = m;
  }
  __syncthreads();  // #1: vT + redA ready
  float gm[4];
  #pragma unroll
  for (int qt = 0; qt < 4; ++qt)
    gm[qt] = fmaxf(fmaxf(redA[0][qt][lr], redA[1][qt][lr]), fmaxf(redA[2][qt][lr], redA[3][qt][lr]));
  #pragma unroll
  for (int qt = 0; qt < 4; ++qt){
    float s = 0.f;
    #pragma unroll
    for (int kt = 0; kt < 4; ++kt){
      bf16x4 pk;
      #pragma unroll
      for (int e = 0; e < 4; ++e){
        float p = __expf((acc[kt][qt][e] - gm[qt]) * 0.25f);
        s += p; pk[e] = (__bf16)p;
      }
      *(bf16x4*)(P_s + (size_t)(qt * 16 + lr) * 264 + w * 64 + kt * 16 + lg * 4) = pk;
    }
    s += __shfl_xor(s, 16); s += __shfl_xor(s, 32);
    if (l < 16) redB[w][qt][lr] = s;
  }
  __syncthreads();  // #2: P + redB ready
  if (tid < 64){
    int qt = tid >> 4, r = tid & 15;
    den[tid] = redB[0][qt][r] + redB[1][qt][r] + redB[2][qt][r] + redB[3][qt][r];
  }
  // ---- ligand PV: ctx_l partial over this wave's key slab ----
  {
    f32x4 o[4];
    #pragma unroll
    for (int qt = 0; qt < 4; ++qt) o[qt] = (f32x4){0.f,0.f,0.f,0.f};
    #pragma unroll
    for (int ks = 0; ks < 2; ++ks){
      int kb = w * 64 + ks * 32;
      bf16x8 bfr2 = *(const bf16x8*)(vT_s + (size_t)lr * 264 + kb + lg * 8);
      #pragma unroll
      for (int qt = 0; qt < 4; ++qt){
        bf16x8 afr2 = *(const bf16x8*)(P_s + (size_t)(qt * 16 + lr) * 264 + kb + lg * 8);
        o[qt] = __builtin_amdgcn_mfma_f32_16x16x32_bf16(afr2, bfr2, o[qt], 0, 0, 0);
      }
    }
    #pragma unroll
    for (int qt = 0; qt < 4; ++qt)
      #pragma unroll
      for (int e = 0; e < 4; ++e)
        cpart[w][qt * 16 + lg * 4 + e][lr] = o[qt][e];
  }
  __syncthreads();  // #3: cpart + den ready
  {
    int q = tid >> 2, dg = (tid & 3) * 4;
    float inv = 1.f / den[q];
    bf16x4 ov;
    #pragma unroll
    for (int jj = 0; jj < 4; ++jj)
      ov[jj] = (__bf16)((cpart[0][q][dg+jj] + cpart[1][q][dg+jj] + cpart[2][q][dg+jj] + cpart[3][q][dg+jj]) * inv);
    *(bf16x4*)(ctx_l + (size_t)(b * LPB + q) * DMODEL + h * 16 + dg) = ov;
  }
  __syncthreads();  // #4: den/P_s/vT_s free for reuse

  // ---- protein side: queries split across waves, all 64 ligand keys in-wave ----
  if (tid < 64){
    const u16* src = ql + (size_t)tid * 384 + 256 + h * 16;
    bf16x8 v0 = *(const bf16x8*)src;
    bf16x8 v1 = *(const bf16x8*)(src + 8);
    #pragma unroll
    for (int i = 0; i < 8; ++i){
      vT_s[i * 72 + tid]       = ((const u16*)&v0)[i];
      vT_s[(i + 8) * 72 + tid] = ((const u16*)&v1)[i];
    }
  }
  f32x4 acc2[4][4];
  #pragma unroll
  for (int kt = 0; kt < 4; ++kt)
    #pragma unroll
    for (int qq = 0; qq < 4; ++qq) acc2[kt][qq] = (f32x4){0.f,0.f,0.f,0.f};
  {
    bf16x8 afr[4], bfr[4];
    #pragma unroll
    for (int kt = 0; kt < 4; ++kt)
      afr[kt] = (l < 32) ? *(const bf16x8*)(ql + (size_t)(kt * 16 + lr) * 384 + 128 + h * 16 + lg * 8) : zero8;
    #pragma unroll
    for (int qq = 0; qq < 4; ++qq)
      bfr[qq] = (l < 32) ? *(const bf16x8*)(qp + (size_t)((w * 4 + qq) * 16 + lr) * 384 + h * 16 + lg * 8) : zero8;
    #pragma unroll
    for (int kt = 0; kt < 4; ++kt)
      #pragma unroll
      for (int qq = 0; qq < 4; ++qq)
        acc2[kt][qq] = __builtin_amdgcn_mfma_f32_16x16x32_bf16(afr[kt], bfr[qq], acc2[kt][qq], 0, 0, 0);
  }
  float pm2[4];
  #pragma unroll
  for (int qq = 0; qq < 4; ++qq){
    float m = -1e30f;
    #pragma unroll
    for (int kt = 0; kt < 4; ++kt)
      #pragma unroll
      for (int e = 0; e < 4; ++e) m = fmaxf(m, acc2[kt][qq][e]);
    m = fmaxf(m, __shfl_xor(m, 16)); m = fmaxf(m, __shfl_xor(m, 32));
    pm2[qq] = m;
  }
  #pragma unroll
  for (int qq = 0; qq < 4; ++qq){
    float s = 0.f;
    #pragma unroll
    for (int kt = 0; kt < 4; ++kt){
      bf16x4 pk;
      #pragma unroll
      for (int e = 0; e < 4; ++e){
        float p = __expf((acc2[kt][qq][e] - pm2[qq]) * 0.25f);
        s += p; pk[e] = (__bf16)p;
      }
      *(bf16x4*)(P_s + (size_t)((w * 4 + qq) * 16 + lr) * 72 + kt * 16 + lg * 4) = pk;
    }
    s += __shfl_xor(s, 16); s += __shfl_xor(s, 32);
    if (l < 16) den[(w * 4 + qq) * 16 + lr] = s;
  }
  __syncthreads();  // #5: prot P + vT + den ready
  {
    f32x4 o2[4];
    #pragma unroll
    for (int qq = 0; qq < 4; ++qq) o2[qq] = (f32x4){0.f,0.f,0.f,0.f};
    #pragma unroll
    for (int ks = 0; ks < 2; ++ks){
      int kb = ks * 32;
      bf16x8 bfr2 = *(const bf16x8*)(vT_s + (size_t)lr * 72 + kb + lg * 8);
      #pragma unroll
      for (int qq = 0; qq < 4; ++qq){
        bf16x8 afr2 = *(const bf16x8*)(P_s + (size_t)((w * 4 + qq) * 16 + lr) * 72 + kb + lg * 8);
        o2[qq] = __builtin_amdgcn_mfma_f32_16x16x32_bf16(afr2, bfr2, o2[qq], 0, 0, 0);
      }
    }
    #pragma unroll
    for (int qq = 0; qq < 4; ++qq)
      #pragma unroll
      for (int e = 0; e < 4; ++e){
        int q = (w * 4 + qq) * 16 + lg * 4 + e;
        ctx_p[(size_t)(b * PPB + q) * DMODEL + h * 16 + lr] = f2bf(o2[qq][e] / den[q]);
      }
  }
}

// ---------------- fused tail: gate+u GEMM -> gating -> LN -> FFN1 -> FFN2 ----------------
struct TailArgs {
  const u16 *ctx_bf[2];
  const float *h_f[2];
  const u16 *WgT[2], *WgB[2], *WuT[2];
  const float *bg[2], *bu[2], *lng[2], *lnb[2];
  const u16 *W1T[2], *W2T[2];
  const float *b1[2], *b2[2];
  float* out[2];
};

__global__ __launch_bounds__(256) void tail_kernel(TailArgs args){
  __shared__ float hu_s[TR][132];
  __shared__ u16 xln_s[TR][136];
  __shared__ u16 t_s[TR][520];

  int bid = (int)blockIdx.x;
  int side = (bid < NPROT / TR) ? 0 : 1;
  int rowbase = (side ? bid - NPROT / TR : bid) * TR;
  int w = (int)threadIdx.x >> 6;
  int l = (int)threadIdx.x & 63;
  int lr = l & 15;
  int lk = (l >> 4) * 8;

  // ---- stage 1: glin (K=256: h|ctx) and u (K=128: ctx) ----
  {
    f32x4 g[2][2], u[2][2];
    #pragma unroll
    for (int i = 0; i < 2; ++i)
      #pragma unroll
      for (int jj = 0; jj < 2; ++jj){ g[i][jj] = (f32x4){0.f,0.f,0.f,0.f}; u[i][jj] = g[i][jj]; }
    const float* Ahf = args.h_f[side] + (size_t)(rowbase + lr) * 128 + lk;
    const __bf16* Ac = (const __bf16*)args.ctx_bf[side] + (size_t)(rowbase + lr) * 128 + lk;
    const __bf16* Bg = (const __bf16*)args.WgT[side] + (size_t)(w * 32 + lr) * 128 + lk;
    const __bf16* Bc = (const __bf16*)args.WgB[side] + (size_t)(w * 32 + lr) * 128 + lk;
    const __bf16* Bu = (const __bf16*)args.WuT[side] + (size_t)(w * 32 + lr) * 128 + lk;
    #pragma unroll
    for (int kk = 0; kk < 128; kk += 32){
      bf16x8 ah0 = cvt8(Ahf + kk);
      bf16x8 ah1 = cvt8(Ahf + 16 * 128 + kk);
      bf16x8 ac0 = *(const bf16x8*)(Ac + kk);
      bf16x8 ac1 = *(const bf16x8*)(Ac + 16 * 128 + kk);
      bf16x8 bg0 = *(const bf16x8*)(Bg + kk);
      bf16x8 bg1 = *(const bf16x8*)(Bg + 16 * 128 + kk);
      bf16x8 bc0 = *(const bf16x8*)(Bc + kk);
      bf16x8 bc1 = *(const bf16x8*)(Bc + 16 * 128 + kk);
      bf16x8 bu0 = *(const bf16x8*)(Bu + kk);
      bf16x8 bu1 = *(const bf16x8*)(Bu + 16 * 128 + kk);
      g[0][0] = __builtin_amdgcn_mfma_f32_16x16x32_bf16(ah0, bg0, g[0][0], 0, 0, 0);
      g[0][1] = __builtin_amdgcn_mfma_f32_16x16x32_bf16(ah0, bg1, g[0][1], 0, 0, 0);
      g[1][0] = __builtin_amdgcn_mfma_f32_16x16x32_bf16(ah1, bg0, g[1][0], 0, 0, 0);
      g[1][1] = __builtin_amdgcn_mfma_f32_16x16x32_bf16(ah1, bg1, g[1][1], 0, 0, 0);
      g[0][0] = __builtin_amdgcn_mfma_f32_16x16x32_bf16(ac0, bc0, g[0][0], 0, 0, 0);
      g[0][1] = __builtin_amdgcn_mfma_f32_16x16x32_bf16(ac0, bc1, g[0][1], 0, 0, 0);
      g[1][0] = __builtin_amdgcn_mfma_f32_16x16x32_bf16(ac1, bc0, g[1][0], 0, 0, 0);
      g[1][1] = __builtin_amdgcn_mfma_f32_16x16x32_bf16(ac1, bc1, g[1][1], 0, 0, 0);
      u[0][0] = __builtin_amdgcn_mfma_f32_16x16x32_bf16(ac0, bu0, u[0][0], 0, 0, 0);
      u[0][1] = __builtin_amdgcn_mfma_f32_16x16x32_bf16(ac0, bu1, u[0][1], 0, 0, 0);
      u[1][0] = __builtin_amdgcn_mfma_f32_16x16x32_bf16(ac1, bu0, u[1][0], 0, 0, 0);
      u[1][1] = __builtin_amdgcn_mfma_f32_16x16x32_bf16(ac1, bu1, u[1][1], 0, 0, 0);
    }
    const float* hf = args.h_f[side];
    const float* bgv = args.bg[side];
    const float* buv = args.bu[side];
    #pragma unroll
    for (int i = 0; i < 2; ++i)
      #pragma unroll
      for (int jj = 0; jj < 2; ++jj)
        #pragma unroll
        for (int e = 0; e < 4; ++e){
          int row = i * 16 + ((l >> 4) << 2) + e;
          int col = w * 32 + jj * 16 + lr;
          float gv = g[i][jj][e] + bgv[col];
          float uv = u[i][jj][e] + buv[col];
          float hv = hf[(size_t)(rowbase + row) * 128 + col];
          float sg = 1.f / (1.f + __expf(-gv));
          hu_s[row][col] = hv + sg * uv;
        }
  }
  __syncthreads();

  // ---- stage 2: LayerNorm -> xln (bf16, XOR-swizzled) ----
  {
    int r = (int)threadIdx.x >> 3;
    int sub = (int)threadIdx.x & 7;
    float x[16];
    #pragma unroll
    for (int i = 0; i < 4; ++i){
      float4 v4 = *(const float4*)&hu_s[r][sub * 16 + i * 4];
      x[i*4+0] = v4.x; x[i*4+1] = v4.y; x[i*4+2] = v4.z; x[i*4+3] = v4.w;
    }
    float s = 0.f;
    #pragma unroll
    for (int i = 0; i < 16; ++i) s += x[i];
    s += __shfl_xor(s, 1); s += __shfl_xor(s, 2); s += __shfl_xor(s, 4);
    float mu = s * (1.f / 128.f);
    float vv = 0.f;
    #pragma unroll
    for (int i = 0; i < 16; ++i){ float d = x[i] - mu; vv += d * d; }
    vv += __shfl_xor(vv, 1); vv += __shfl_xor(vv, 2); vv += __shfl_xor(vv, 4);
    float rs = rsqrtf(vv * (1.f / 128.f) + 1e-5f);
    const float* lg2 = args.lng[side];
    const float* lb = args.lnb[side];
    int sw = (r & 7) << 3;
    #pragma unroll
    for (int i = 0; i < 16; ++i){
      int col = sub * 16 + i;
      xln_s[r][col ^ sw] = f2bf((x[i] - mu) * rs * lg2[col] + lb[col]);
    }
  }
  __syncthreads();

  // ---- stage 3: FFN1 t = relu(xln @ W1 + b1) ----
  {
    f32x4 acc[2][8];
    #pragma unroll
    for (int i = 0; i < 2; ++i)
      #pragma unroll
      for (int jj = 0; jj < 8; ++jj) acc[i][jj] = (f32x4){0.f,0.f,0.f,0.f};
    const __bf16* B1 = (const __bf16*)args.W1T[side] + (size_t)(w * 128 + lr) * 128 + lk;
    int sw0 = (lr & 7) << 3;
    #pragma unroll
    for (int kk = 0; kk < 128; kk += 32){
      bf16x8 a0 = *(const bf16x8*)&xln_s[lr][(kk + lk) ^ sw0];
      bf16x8 a1 = *(const bf16x8*)&xln_s[16 + lr][(kk + lk) ^ sw0];
      #pragma unroll
      for (int jj = 0; jj < 8; ++jj){
        bf16x8 bb = *(const bf16x8*)(B1 + (size_t)jj * 16 * 128 + kk);
        acc[0][jj] = __builtin_amdgcn_mfma_f32_16x16x32_bf16(a0, bb, acc[0][jj], 0, 0, 0);
        acc[1][jj] = __builtin_amdgcn_mfma_f32_16x16x32_bf16(a1, bb, acc[1][jj], 0, 0, 0);
      }
    }
    const float* b1v = args.b1[side];
    #pragma unroll
    for (int i = 0; i < 2; ++i)
      #pragma unroll
      for (int jj = 0; jj < 8; ++jj)
        #pragma unroll
        for (int e = 0; e < 4; ++e){
          int row = i * 16 + ((l >> 4) << 2) + e;
          int col = w * 128 + jj * 16 + lr;
          float v = fmaxf(acc[i][jj][e] + b1v[col], 0.f);
          t_s[row][col ^ ((row & 7) << 3)] = f2bf(v);
        }
  }
  __syncthreads();

  // ---- stage 4: FFN2 out = t @ W2 + b2 + hu ----
  {
    f32x4 o[2][2];
    #pragma unroll
    for (int i = 0; i < 2; ++i)
      #pragma unroll
      for (int jj = 0; jj < 2; ++jj) o[i][jj] = (f32x4){0.f,0.f,0.f,0.f};
    const __bf16* B2 = (const __bf16*)args.W2T[side] + (size_t)(w * 32 + lr) * 512 + lk;
    int sw0 = (lr & 7) << 3;
    #pragma unroll
    for (int kk = 0; kk < 512; kk += 32){
      bf16x8 a0 = *(const bf16x8*)&t_s[lr][(kk + lk) ^ sw0];
      bf16x8 a1 = *(const bf16x8*)&t_s[16 + lr][(kk + lk) ^ sw0];
      bf16x8 b0 = *(const bf16x8*)(B2 + kk);
      bf16x8 b1 = *(const bf16x8*)(B2 + (size_t)16 * 512 + kk);
      o[0][0] = __builtin_amdgcn_mfma_f32_16x16x32_bf16(a0, b0, o[0][0], 0, 0, 0);
      o[0][1] = __builtin_amdgcn_mfma_f32_16x16x32_bf16(a0, b1, o[0][1], 0, 0, 0);
      o[1][0] = __builtin_amdgcn_mfma_f32_16x16x32_bf16(a1, b0, o[1][0], 0, 0, 0);
      o[1][1] = __builtin_amdgcn_mfma_f32_16x16x32_bf16(a1, b1, o[1][1], 0, 0, 0);
    }
    const float* b2v = args.b2[side];
    float* outp = args.out[side];
    #pragma unroll
    for (int i = 0; i < 2; ++i)
      #pragma unroll
      for (int jj = 0; jj < 2; ++jj)
        #pragma unroll
        for (int e = 0; e < 4; ++e){
          int row = i * 16 + ((l >> 4) << 2) + e;
          int col = w * 32 + jj * 16 + lr;
          outp[(size_t)(rowbase + row) * 128 + col] = o[i][jj][e] + b2v[col] + hu_s[row][col];
        }
  }
}

// ---------------- host ----------------
extern "C" void kernel_launch(void* const* d_in, const int* in_sizes, int n_in,
                              void* d_out, int out_size, void* d_ws, size_t ws_size,
                              hipStream_t stream) {
  (void)in_sizes; (void)n_in; (void)out_size; (void)ws_size;
  const float* h_p  = (const float*)d_in[0];
  const float* h_l  = (const float*)d_in[1];
  const float* Wq_l = (const float*)d_in[4];
  const float* Wk_p = (const float*)d_in[5];
  const float* Wv_p = (const float*)d_in[6];
  const float* Wg_l = (const float*)d_in[7];
  const float* bg_l = (const float*)d_in[8];
  const float* Wu_l = (const float*)d_in[9];
  const float* bu_l = (const float*)d_in[10];
  const float* Wq_p = (const float*)d_in[11];
  const float* Wk_l = (const float*)d_in[12];
  const float* Wv_l = (const float*)d_in[13];
  const float* Wg_p = (const float*)d_in[14];
  const float* bg_p = (const float*)d_in[15];
  const float* Wu_p = (const float*)d_in[16];
  const float* bu_p = (const float*)d_in[17];
  const float* ln_p_g = (const float*)d_in[18];
  const float* ln_p_b = (const float*)d_in[19];
  const float* ln_l_g = (const float*)d_in[20];
  const float* ln_l_b = (const float*)d_in[21];
  const float* W1_p = (const float*)d_in[22];
  const float* b1_p = (const float*)d_in[23];
  const float* W2_p = (const float*)d_in[24];
  const float* b2_p = (const float*)d_in[25];
  const float* W1_l = (const float*)d_in[26];
  const float* b1_l = (const float*)d_in[27];
  const float* W2_l = (const float*)d_in[28];
  const float* b2_l = (const float*)d_in[29];
  float* out = (float*)d_out;

  char* ws = (char*)d_ws;
  size_t off = 0;
  auto alloc = [&](size_t bytes) -> void* {
    void* p = ws + off; off += (bytes + 255) & ~(size_t)255; return p;
  };
  u16* projP_T = (u16*)alloc((size_t)384 * 128 * 2);
  u16* projL_T = (u16*)alloc((size_t)384 * 128 * 2);
  u16* WgT_p_T = (u16*)alloc((size_t)128 * 128 * 2);
  u16* WgB_p_T = (u16*)alloc((size_t)128 * 128 * 2);
  u16* Wu_p_T  = (u16*)alloc((size_t)128 * 128 * 2);
  u16* WgT_l_T = (u16*)alloc((size_t)128 * 128 * 2);
  u16* WgB_l_T = (u16*)alloc((size_t)128 * 128 * 2);
  u16* Wu_l_T  = (u16*)alloc((size_t)128 * 128 * 2);
  u16* W1_p_T  = (u16*)alloc((size_t)512 * 128 * 2);
  u16* W1_l_T  = (u16*)alloc((size_t)512 * 128 * 2);
  u16* W2_p_T  = (u16*)alloc((size_t)128 * 512 * 2);
  u16* W2_l_T  = (u16*)alloc((size_t)128 * 512 * 2);
  u16* qkv_p   = (u16*)alloc((size_t)NPROT * 384 * 2);
  u16* qkv_l   = (u16*)alloc((size_t)NLIG  * 384 * 2);
  u16* ctx_p_bf = (u16*)alloc((size_t)NPROT * DMODEL * 2);
  u16* ctx_l_bf = (u16*)alloc((size_t)NLIG  * DMODEL * 2);

  // ---- prep (weights only, tiled transpose) ----
  TArgs ta; ta.njobs = 16;
  int tbs = 0;
  auto addT = [&](int i, const float* s, u16* d, int K, int M){
    ta.jobs[i].src = s; ta.jobs[i].dst = d; ta.jobs[i].M = M; ta.jobs[i].K = K;
    ta.jobs[i].tilesX = M / 32; ta.jobs[i].blockStart = tbs;
    tbs += (K / 32) * (M / 32);
  };
  addT(0,  Wq_l, projL_T + 0,         128, 128);
  addT(1,  Wk_l, projL_T + 128 * 128, 128, 128);
  addT(2,  Wv_l, projL_T + 256 * 128, 128, 128);
  addT(3,  Wq_p, projP_T + 0,         128, 128);
  addT(4,  Wk_p, projP_T + 128 * 128, 128, 128);
  addT(5,  Wv_p, projP_T + 256 * 128, 128, 128);
  addT(6,  Wg_l,             WgT_l_T, 128, 128);
  addT(7,  Wg_l + 128 * 128, WgB_l_T, 128, 128);
  addT(8,  Wu_l,             Wu_l_T,  128, 128);
  addT(9,  Wg_p,             WgT_p_T, 128, 128);
  addT(10, Wg_p + 128 * 128, WgB_p_T, 128, 128);
  addT(11, Wu_p,             Wu_p_T,  128, 128);
  addT(12, W1_p, W1_p_T, 128, 512);
  addT(13, W2_p, W2_p_T, 512, 128);
  addT(14, W1_l, W1_l_T, 128, 512);
  addT(15, W2_l, W2_l_T, 512, 128);
  prep_kernel<<<dim3(tbs), dim3(256), 0, stream>>>(ta);

  // ---- QKV projections ----
  {
    QkvArgs qa;
    qa.jobs[0] = { h_p, projP_T, qkv_p, 0 };
    qa.jobs[1] = { h_l, projL_T, qkv_l, (NPROT / 64) * 6 };
    int nb = (NPROT / 64) * 6 + (NLIG / 64) * 6;
    qkv_kernel<<<dim3(nb), dim3(256), 0, stream>>>(qa);
  }

  // ---- fused MFMA attention (both directions) ----
  attn_kernel<<<dim3(NBATCH * NHEAD), dim3(256), 0, stream>>>(qkv_p, qkv_l, ctx_p_bf, ctx_l_bf);

  // ---- fused tail ----
  {
    TailArgs tl;
    tl.ctx_bf[0] = ctx_p_bf; tl.ctx_bf[1] = ctx_l_bf;
    tl.h_f[0] = h_p; tl.h_f[1] = h_l;
    tl.WgT[0] = WgT_p_T; tl.WgT[1] = WgT_l_T;
    tl.WgB[0] = WgB_p_T; tl.WgB[1] = WgB_l_T;
    tl.WuT[0] = Wu_p_T;  tl.WuT[1] = Wu_l_T;
    tl.bg[0] = bg_p; tl.bg[1] = bg_l;
    tl.bu[0] = bu_p; tl.bu[1] = bu_l;
    tl.lng[0] = ln_p_g; tl.lng[1] = ln_l_g;
    tl.lnb[0] = ln_p_b; tl.lnb[1] = ln_l_b;
    tl.W1T[0] = W1_p_T; tl.W1T[1] = W1_l_T;
    tl.W2T[0] = W2_p_T; tl.W2T[1] = W2_l_T;
    tl.b1[0] = b1_p; tl.b1[1] = b1_l;
    tl.b2[0] = b2_p; tl.b2[1] = b2_l;
    tl.out[0] = out; tl.out[1] = out + (size_t)NPROT * DMODEL;
    tail_kernel<<<dim3(NPROT / TR + NLIG / TR), dim3(256), 0, stream>>>(tl);
  }
}